// Round 1
// baseline (16715.428 us; speedup 1.0000x reference)
//
#include <hip/hip_runtime.h>
#include <hip/hip_fp16.h>

namespace {

constexpr int kIn     = 64;
constexpr int kHid    = 128;
constexpr int kOut    = 64;
constexpr int kT      = 1000;
constexpr int kTC     = 8;          // timesteps per staging chunk
constexpr int kChunks = kT / kTC;
constexpr int kBatch  = 256;

__device__ __forceinline__ float sigm(float v)   { return 1.0f / (1.0f + __expf(-v)); }
__device__ __forceinline__ float tanhf_(float v) { return 2.0f / (1.0f + __expf(-2.0f * v)) - 1.0f; }

// XOR-swizzle of 16B chunks within an LDS array (involution): spreads the
// stride-64B float4 fragment reads across banks. Apply to ALL reads+writes
// of su/sh/srh/szg/sha. Offsets are precomputed outside the t-loop.
__device__ __forceinline__ int swzi(int i) {          // float index -> float index
  const int c = i >> 2;
  return ((c ^ ((c >> 3) & 7)) << 2) | (i & 3);
}
__device__ __forceinline__ int swzc(int c) {          // chunk index -> float offset
  return (c ^ ((c >> 3) & 7)) << 2;
}
// column-local mapping produced by the reduce-scatter butterflies
__device__ __forceinline__ int cl8(int k) { return ((k & 1) << 2) | (k & 2) | ((k >> 2) & 1); }
__device__ __forceinline__ int cl4(int k) { return ((k & 1) << 1) | ((k >> 1) & 1); }

// reduce-scatter 8 accumulators across 8 lanes (lane bits = kl). After this,
// each lane holds the full 8-lane sum for column cl8(kl).
__device__ __forceinline__ float rs8(float a0, float a1, float a2, float a3,
                                     float a4, float a5, float a6, float a7, int kl) {
  float t0, t1, t2, t3;
  {
    const bool hi = kl & 1;
    const float s0 = hi ? a0 : a4, s1 = hi ? a1 : a5, s2 = hi ? a2 : a6, s3 = hi ? a3 : a7;
    t0 = (hi ? a4 : a0) + __shfl_xor(s0, 1);
    t1 = (hi ? a5 : a1) + __shfl_xor(s1, 1);
    t2 = (hi ? a6 : a2) + __shfl_xor(s2, 1);
    t3 = (hi ? a7 : a3) + __shfl_xor(s3, 1);
  }
  float u0, u1;
  {
    const bool hi = kl & 2;
    const float s0 = hi ? t0 : t2, s1 = hi ? t1 : t3;
    u0 = (hi ? t2 : t0) + __shfl_xor(s0, 2);
    u1 = (hi ? t3 : t1) + __shfl_xor(s1, 2);
  }
  {
    const bool hi = kl & 4;
    const float s = hi ? u0 : u1;
    return (hi ? u1 : u0) + __shfl_xor(s, 4);
  }
}

// reduce-scatter 4 accumulators across 4 lanes (lane bits = kl). Result is the
// 4-lane partial for column cl4(kl); caller adds the remaining xor steps.
__device__ __forceinline__ float rs4(float a0, float a1, float a2, float a3, int kl) {
  float t0, t1;
  {
    const bool hi = kl & 1;
    const float s0 = hi ? a0 : a2, s1 = hi ? a1 : a3;
    t0 = (hi ? a2 : a0) + __shfl_xor(s0, 1);
    t1 = (hi ? a3 : a1) + __shfl_xor(s1, 1);
  }
  {
    const bool hi = kl & 2;
    const float s = hi ? t0 : t1;
    return (hi ? t1 : t0) + __shfl_xor(s, 2);
  }
}

// load 16 floats (4 swizzled 16B chunks) from LDS
__device__ __forceinline__ void ld16(const float* base, const int off[4], float* v) {
  const float4 c0 = *reinterpret_cast<const float4*>(base + off[0]);
  const float4 c1 = *reinterpret_cast<const float4*>(base + off[1]);
  const float4 c2 = *reinterpret_cast<const float4*>(base + off[2]);
  const float4 c3 = *reinterpret_cast<const float4*>(base + off[3]);
  v[0]=c0.x; v[1]=c0.y; v[2]=c0.z;  v[3]=c0.w;
  v[4]=c1.x; v[5]=c1.y; v[6]=c1.z;  v[7]=c1.w;
  v[8]=c2.x; v[9]=c2.y; v[10]=c2.z; v[11]=c2.w;
  v[12]=c3.x; v[13]=c3.y; v[14]=c3.z; v[15]=c3.w;
}

// One block per batch row. 512 threads = 8 waves, 1 block/CU.
// 3-barrier pipelined timestep:
//   SEG1: publish su = [x'|m|gamma_h*h] (waves 4-6, gamma dots were precomputed
//         in SEG3 of t-1); wave 7 computes y(t-1); waves 0-2 handle staging.
//   SEG2: z/r dots (all waves) + h_tilde x/m dot (waves 0-3); butterfly
//         reductions in-register; publish szg/srh/sha.
//   SEG3: Whh dot + h update + outH (waves 0-3) || gamma dots for t+1
//         (waves 4-6, kept in registers across the barrier).
// All cross-phase LDS arrays are 16B-chunk XOR-swizzled (bank conflicts).
__global__ __launch_bounds__(512, 1) void grud_persistent(
    const float* __restrict__ gIn,
    const float* __restrict__ xMean,
    const float* __restrict__ Wdgx, const float* __restrict__ bdgx,
    const float* __restrict__ Wdgh, const float* __restrict__ bdgh,
    const float* __restrict__ Wxz,  const float* __restrict__ Whz,
    const float* __restrict__ Wmz,  const float* __restrict__ bmz,
    const float* __restrict__ Wxr,  const float* __restrict__ Whr,
    const float* __restrict__ Wmr,
    const float* __restrict__ Wxh,  const float* __restrict__ Whh,
    const float* __restrict__ Wmh,  const float* __restrict__ bmh,
    const float* __restrict__ Why,  const float* __restrict__ bhy,
    float* __restrict__ out)
{
  const int tid = threadIdx.x;
  const int b   = blockIdx.x;

  __shared__ __align__(16) float sX[2][kTC][kIn];
  __shared__ __align__(16) float sM[2][kTC][kIn];
  __shared__ __align__(16) float sD[2][kTC][kIn];
  __shared__ __align__(16) float su[2 * kHid];   // swizzled: [x'(64)|m(64)|gh*h(128)]
  __shared__ __align__(16) float sh[kHid];       // swizzled: hidden state
  __shared__ __align__(16) float srh[kHid];      // swizzled: r * (gh*h)
  __shared__ __align__(16) float szg[kHid];      // swizzled: z gate
  __shared__ __align__(16) float sha[kHid];      // swizzled: x'/m part of h_tilde preact

  // ---------------- register-resident weights (packed f16 pairs) ----------------
  __half2 wZR[8][8];    // all: z-concat (tid<256) or r-concat (tid>=256); 8 cols x 16 k
  __half2 wHA[4][8];    // tid<256: [Wxh;Wmh]; 4 cols x 16 k
  __half2 wRole[64];    // tid<256: Whh 4x8 | 256..383: Wdgh 8x4 | 384..447: Wdgx 8x4 | >=448: Why 8x8

  {
    const int lt = tid & 255;
    const int kc = lt & 15, cg = lt >> 4;
    const float* Wx = (tid < 256) ? Wxz : Wxr;
    const float* Wm = (tid < 256) ? Wmz : Wmr;
    const float* Wh = (tid < 256) ? Whz : Whr;
#pragma unroll
    for (int c = 0; c < 8; ++c) {
      const int j = cg * 8 + c;
#pragma unroll
      for (int p = 0; p < 8; ++p) {
        const int k = kc * 16 + 2 * p;
        const float a0 = (k < 64) ? Wx[k * kHid + j]
                        : (k < 128) ? Wm[(k - 64) * kHid + j]
                                    : Wh[(k - 128) * kHid + j];
        const float a1 = (k + 1 < 64) ? Wx[(k + 1) * kHid + j]
                        : (k + 1 < 128) ? Wm[(k + 1 - 64) * kHid + j]
                                        : Wh[(k + 1 - 128) * kHid + j];
        wZR[c][p] = __floats2half2_rn(a0, a1);
      }
    }
  }
  if (tid < 256) {                       // wHA + Whh, same (kc, grp) geometry
    const int kc = tid & 7, grp = tid >> 3;
#pragma unroll
    for (int c = 0; c < 4; ++c) {
      const int j = grp * 4 + c;
#pragma unroll
      for (int p = 0; p < 8; ++p) {
        const int k = kc * 16 + 2 * p;
        const float a0 = (k < 64) ? Wxh[k * kHid + j] : Wmh[(k - 64) * kHid + j];
        const float a1 = (k + 1 < 64) ? Wxh[(k + 1) * kHid + j] : Wmh[(k + 1 - 64) * kHid + j];
        wHA[c][p]       = __floats2half2_rn(a0, a1);
        wRole[c * 8 + p] = __floats2half2_rn(Whh[k * kHid + j], Whh[(k + 1) * kHid + j]);
      }
    }
  } else if (tid < 384) {                // Wdgh
    const int lt = tid - 256, kc = lt & 7, cg = lt >> 3;
#pragma unroll
    for (int c = 0; c < 8; ++c) {
      const int j = cg * 8 + c;
#pragma unroll
      for (int p = 0; p < 4; ++p) {
        const int k = kc * 8 + 2 * p;
        wRole[c * 4 + p] = __floats2half2_rn(Wdgh[k * kHid + j], Wdgh[(k + 1) * kHid + j]);
      }
    }
  } else if (tid < 448) {                // Wdgx
    const int lt = tid - 384, kc = lt & 7, cg = lt >> 3;
#pragma unroll
    for (int c = 0; c < 8; ++c) {
      const int i = cg * 8 + c;
#pragma unroll
      for (int p = 0; p < 4; ++p) {
        const int k = kc * 8 + 2 * p;
        wRole[c * 4 + p] = __floats2half2_rn(Wdgx[k * kIn + i], Wdgx[(k + 1) * kIn + i]);
      }
    }
  } else {                               // Why
    const int lt = tid - 448, kc = lt & 7, cg = lt >> 3;
#pragma unroll
    for (int c = 0; c < 8; ++c) {
      const int o = cg * 8 + c;
#pragma unroll
      for (int p = 0; p < 8; ++p) {
        const int k = kc * 16 + 2 * p;
        wRole[c * 8 + p] = __floats2half2_rn(Why[k * kOut + o], Why[(k + 1) * kOut + o]);
      }
    }
  }

  // ---------------- per-thread constants (precomputed, loop-invariant) ----------------
  const int kcZ = tid & 15;
  const int jZR = ((tid & 255) >> 4) * 8 + cl8(kcZ & 7);   // z/r output column
  const int kcH = tid & 7;
  const int colH = ((tid & 255) >> 3) * 4 + cl4(kcH & 3);  // HA/HH output column (tid<256)

  float bZ = 0.0f, bA = 0.0f;
  int idx_zw = 0, idx_rw = 0, idx_su128r = 0, idx_colH = 0, idx_hp = 0;
  if (tid < 256) {
    bZ = bmz[jZR];  idx_zw = swzi(jZR);
    bA = bmh[colH]; idx_colH = swzi(colH); idx_hp = swzi(128 + colH);
  } else {
    idx_rw = swzi(jZR); idx_su128r = swzi(128 + jZR);
  }

  int suOff[4], off16[4];
#pragma unroll
  for (int q = 0; q < 4; ++q) {
    suOff[q] = swzc(4 * kcZ + q);   // z/r input: su chunks (K=256)
    off16[q] = swzc(4 * kcH + q);   // HA(su[0:128]) / HH(srh) / Y(sh) chunks (K=128)
  }

  float bG = 0.0f, xmv = 0.0f, bY = 0.0f;
  int colI = 0, idx_shr = 0, idx_suw = 0, idx_xw = 0, idx_mw = 0, oY = 0;
  if (tid >= 256 && tid < 384) {         // gamma_h owner
    const int lt = tid - 256;
    const int colG = (lt >> 3) * 8 + cl8(lt & 7);
    bG = bdgh[colG]; idx_shr = swzi(colG); idx_suw = swzi(128 + colG);
  } else if (tid >= 384 && tid < 448) {  // gamma_x / x' owner
    const int lt = tid - 384;
    colI = (lt >> 3) * 8 + cl8(lt & 7);
    bG = bdgx[colI]; xmv = xMean[colI];
    idx_xw = swzi(colI); idx_mw = swzi(64 + colI);
  } else if (tid >= 448) {               // y owner
    const int lt = tid - 448;
    oY = (lt >> 3) * 8 + cl8(lt & 7);
    bY = bhy[oY];
  }

  const float* gBase = gIn + (size_t)b * 3 * kIn * kT;
  float* outY = out + (size_t)b * kT * kOut;
  float* outH = out + (size_t)kBatch * kT * kOut + (size_t)b * kT * kHid;

  // gamma dot for the *next* step, computed in SEG3, consumed in SEG1 (register)
  auto gdotCompute = [&](int bs, int ts) -> float {
    const int kc = tid & 7;
    const float4* d4 = reinterpret_cast<const float4*>(&sD[bs][ts][kc * 8]);
    const float4 q0 = d4[0], q1 = d4[1];
    const float dv[8] = {q0.x, q0.y, q0.z, q0.w, q1.x, q1.y, q1.z, q1.w};
    float a[8];
#pragma unroll
    for (int c = 0; c < 8; ++c) {
      float s = 0.0f;
#pragma unroll
      for (int p = 0; p < 4; ++p) {
        const __half2 w = wRole[c * 4 + p];
        s = fmaf(__low2float(w),  dv[2 * p],     s);
        s = fmaf(__high2float(w), dv[2 * p + 1], s);
      }
      a[c] = s;
    }
    return rs8(a[0], a[1], a[2], a[3], a[4], a[5], a[6], a[7], kc);
  };

  auto doY = [&](int ty) {
    float v[16];
    ld16(sh, off16, v);
    float a[8];
#pragma unroll
    for (int c = 0; c < 8; ++c) {
      float s = 0.0f;
#pragma unroll
      for (int p = 0; p < 8; ++p) {
        const __half2 w = wRole[c * 8 + p];
        s = fmaf(__low2float(w),  v[2 * p],     s);
        s = fmaf(__high2float(w), v[2 * p + 1], s);
      }
      a[c] = s;
    }
    const float r = rs8(a[0], a[1], a[2], a[3], a[4], a[5], a[6], a[7], tid & 7);
    outY[(size_t)ty * kOut + oY] = sigm(r + bY);
  };

  // ---------------- prologue: stage chunk 0, init h ----------------
  if (tid < 192) {
    const int c = tid >> 6, i = tid & 63;
    const float4* src = reinterpret_cast<const float4*>(gBase + (size_t)(c * kIn + i) * kT);
    const float4 v0 = src[0], v1 = src[1];
    float* dst = (c == 0) ? &sX[0][0][0] : (c == 1) ? &sM[0][0][0] : &sD[0][0][0];
    dst[0 * kIn + i] = v0.x; dst[1 * kIn + i] = v0.y; dst[2 * kIn + i] = v0.z; dst[3 * kIn + i] = v0.w;
    dst[4 * kIn + i] = v1.x; dst[5 * kIn + i] = v1.y; dst[6 * kIn + i] = v1.z; dst[7 * kIn + i] = v1.w;
  }
  if (tid < kHid) sh[tid] = 0.0f;
  __syncthreads();

  float gdot = 0.0f, xl = 0.0f;
  float4 stv0 = {}, stv1 = {};
  if (tid >= 256 && tid < 448) gdot = gdotCompute(0, 0);

#pragma unroll 1
  for (int t = 0; t < kT; ++t) {
    const int tt  = t & 7;
    const int buf = (t >> 3) & 1;

    // ================= SEG1: publish su; y(t-1); staging =================
    if (tid >= 256 && tid < 384) {
      const float gh = __expf(-fmaxf(gdot + bG, 0.0f));
      su[idx_suw] = gh * sh[idx_shr];
    } else if (tid >= 384 && tid < 448) {
      const float gx = __expf(-fmaxf(gdot + bG, 0.0f));
      const float x = sX[buf][tt][colI];
      const float m = sM[buf][tt][colI];
      xl = (m > 0.0f) ? x : xl;
      su[idx_xw] = m * x + (1.0f - m) * (gx * xl + (1.0f - gx) * xmv);
      su[idx_mw] = m;
    } else if (tid >= 448) {
      if (t > 0) doY(t - 1);
    } else if (tid < 192) {
      if (tt == 0) {
        const int cs = (t >> 3) + 1;           // write staged chunk cs -> buffer cs&1
        if (cs < kChunks) {
          const int c = tid >> 6, i = tid & 63;
          if (t == 0) {                        // cold start: load directly
            const float4* src = reinterpret_cast<const float4*>(
                gBase + (size_t)(c * kIn + i) * kT + cs * kTC);
            stv0 = src[0]; stv1 = src[1];
          }
          float* dst = (c == 0) ? &sX[cs & 1][0][0] : (c == 1) ? &sM[cs & 1][0][0] : &sD[cs & 1][0][0];
          dst[0 * kIn + i] = stv0.x; dst[1 * kIn + i] = stv0.y;
          dst[2 * kIn + i] = stv0.z; dst[3 * kIn + i] = stv0.w;
          dst[4 * kIn + i] = stv1.x; dst[5 * kIn + i] = stv1.y;
          dst[6 * kIn + i] = stv1.z; dst[7 * kIn + i] = stv1.w;
        }
      } else if (tt == 7) {
        const int cs = (t >> 3) + 2;           // issue loads 3 barriers ahead of the write
        if (cs < kChunks) {
          const int c = tid >> 6, i = tid & 63;
          const float4* src = reinterpret_cast<const float4*>(
              gBase + (size_t)(c * kIn + i) * kT + cs * kTC);
          stv0 = src[0]; stv1 = src[1];
        }
      }
    }
    __syncthreads();

    // ================= SEG2: z/r dots (all) + HA dot (waves 0-3) =================
    {
      float u[16];
      ld16(su, suOff, u);
      float a[8];
#pragma unroll
      for (int c = 0; c < 8; ++c) {
        float s = 0.0f;
#pragma unroll
        for (int p = 0; p < 8; ++p) {
          const __half2 w = wZR[c][p];
          s = fmaf(__low2float(w),  u[2 * p],     s);
          s = fmaf(__high2float(w), u[2 * p + 1], s);
        }
        a[c] = s;
      }
      float zr = rs8(a[0], a[1], a[2], a[3], a[4], a[5], a[6], a[7], kcZ & 7);
      zr += __shfl_xor(zr, 8);

      if (tid < 256) {
        float v[16];
        ld16(su, off16, v);                    // su[0:128] = [x'|m]
        float ha[4];
#pragma unroll
        for (int c = 0; c < 4; ++c) {
          float s = 0.0f;
#pragma unroll
          for (int p = 0; p < 8; ++p) {
            const __half2 w = wHA[c][p];
            s = fmaf(__low2float(w),  v[2 * p],     s);
            s = fmaf(__high2float(w), v[2 * p + 1], s);
          }
          ha[c] = s;
        }
        float hv = rs4(ha[0], ha[1], ha[2], ha[3], kcH & 3);
        hv += __shfl_xor(hv, 4);
        if (kcH < 4) sha[idx_colH] = hv + bA;
        if (kcZ < 8) szg[idx_zw] = sigm(zr + bZ);
      } else {
        if (kcZ < 8) srh[idx_rw] = sigm(zr) * su[idx_su128r];
      }
    }
    __syncthreads();

    // ================= SEG3: Whh dot + h update (waves 0-3) || gamma(t+1) (waves 4-6) ==
    if (tid < 256) {
      float v[16];
      ld16(srh, off16, v);
      float a4[4];
#pragma unroll
      for (int c = 0; c < 4; ++c) {
        float s = 0.0f;
#pragma unroll
        for (int p = 0; p < 8; ++p) {
          const __half2 w = wRole[c * 8 + p];
          s = fmaf(__low2float(w),  v[2 * p],     s);
          s = fmaf(__high2float(w), v[2 * p + 1], s);
        }
        a4[c] = s;
      }
      float hh = rs4(a4[0], a4[1], a4[2], a4[3], kcH & 3);
      hh += __shfl_xor(hh, 4);
      if (kcH < 4) {
        const float z   = szg[idx_colH];
        const float hav = sha[idx_colH];
        const float hp  = su[idx_hp];
        const float hn  = (1.0f - z) * hp + z * tanhf_(hav + hh);
        sh[idx_colH] = hn;
        outH[(size_t)t * kHid + colH] = hn;
      }
    } else if (tid < 448) {
      if (t + 1 < kT) {
        const int ttn  = (tt + 1) & 7;
        const int bufn = (tt == 7) ? (buf ^ 1) : buf;
        gdot = gdotCompute(bufn, ttn);
      }
    }
    __syncthreads();
  }

  // epilogue: y for the final step
  if (tid >= 448) doY(kT - 1);
}

} // namespace

extern "C" void kernel_launch(void* const* d_in, const int* in_sizes, int n_in,
                              void* d_out, int out_size, void* d_ws, size_t ws_size,
                              hipStream_t stream) {
  const float* gIn   = (const float*)d_in[0];
  const float* xMean = (const float*)d_in[1];
  const float* Wdgx  = (const float*)d_in[2];
  const float* bdgx  = (const float*)d_in[3];
  const float* Wdgh  = (const float*)d_in[4];
  const float* bdgh  = (const float*)d_in[5];
  const float* Wxz   = (const float*)d_in[6];
  const float* Whz   = (const float*)d_in[7];
  const float* Wmz   = (const float*)d_in[8];
  const float* bmz   = (const float*)d_in[9];
  const float* Wxr   = (const float*)d_in[10];
  const float* Whr   = (const float*)d_in[11];
  const float* Wmr   = (const float*)d_in[12];
  const float* Wxh   = (const float*)d_in[13];
  const float* Whh   = (const float*)d_in[14];
  const float* Wmh   = (const float*)d_in[15];
  const float* bmh   = (const float*)d_in[16];
  const float* Why   = (const float*)d_in[17];
  const float* bhy   = (const float*)d_in[18];

  grud_persistent<<<dim3(256), dim3(512), 0, stream>>>(
      gIn, xMean, Wdgx, bdgx, Wdgh, bdgh, Wxz, Whz, Wmz, bmz,
      Wxr, Whr, Wmr, Wxh, Whh, Wmh, bmh, Why, bhy, (float*)d_out);
}

// Round 2
// 3667.046 us; speedup vs baseline: 4.5583x; 4.5583x over previous
//
#include <hip/hip_runtime.h>
#include <hip/hip_fp16.h>

namespace {

constexpr int kIn     = 64;
constexpr int kHid    = 128;
constexpr int kOut    = 64;
constexpr int kT      = 1000;
constexpr int kTC     = 8;          // timesteps per staging chunk
constexpr int kChunks = kT / kTC;
constexpr int kBatch  = 256;

__device__ __forceinline__ float sigm(float v)   { return 1.0f / (1.0f + __expf(-v)); }
__device__ __forceinline__ float tanhf_(float v) { return 2.0f / (1.0f + __expf(-2.0f * v)) - 1.0f; }

// XOR-swizzle of 16B chunks (involution) for f32 state arrays.
__device__ __forceinline__ int swzi(int i) {          // float index -> float index
  const int c = i >> 2;
  return ((c ^ ((c >> 3) & 7)) << 2) | (i & 3);
}
__device__ __forceinline__ int swzc(int c) {          // chunk index -> float offset
  return (c ^ ((c >> 3) & 7)) << 2;
}
__device__ __forceinline__ int wswz(int c) {          // chunk -> chunk (LDS f16 weights)
  return c ^ ((c >> 3) & 7);
}
// column-local mapping produced by the reduce-scatter butterflies
__device__ __forceinline__ int cl8(int k) { return ((k & 1) << 2) | (k & 2) | ((k >> 2) & 1); }
__device__ __forceinline__ int cl4(int k) { return ((k & 1) << 1) | ((k >> 1) & 1); }

// reduce-scatter 8 accumulators across 8 lanes (lane bits = kl). After this,
// each lane holds the full 8-lane sum for column cl8(kl).
__device__ __forceinline__ float rs8(float a0, float a1, float a2, float a3,
                                     float a4, float a5, float a6, float a7, int kl) {
  float t0, t1, t2, t3;
  {
    const bool hi = kl & 1;
    const float s0 = hi ? a0 : a4, s1 = hi ? a1 : a5, s2 = hi ? a2 : a6, s3 = hi ? a3 : a7;
    t0 = (hi ? a4 : a0) + __shfl_xor(s0, 1);
    t1 = (hi ? a5 : a1) + __shfl_xor(s1, 1);
    t2 = (hi ? a6 : a2) + __shfl_xor(s2, 1);
    t3 = (hi ? a7 : a3) + __shfl_xor(s3, 1);
  }
  float u0, u1;
  {
    const bool hi = kl & 2;
    const float s0 = hi ? t0 : t2, s1 = hi ? t1 : t3;
    u0 = (hi ? t2 : t0) + __shfl_xor(s0, 2);
    u1 = (hi ? t3 : t1) + __shfl_xor(s1, 2);
  }
  {
    const bool hi = kl & 4;
    const float s = hi ? u0 : u1;
    return (hi ? u1 : u0) + __shfl_xor(s, 4);
  }
}

// reduce-scatter 4 accumulators across 4 lanes (lane bits = kl): 4-lane partial
// for column cl4(kl); caller adds the remaining xor step(s).
__device__ __forceinline__ float rs4(float a0, float a1, float a2, float a3, int kl) {
  float t0, t1;
  {
    const bool hi = kl & 1;
    const float s0 = hi ? a0 : a2, s1 = hi ? a1 : a3;
    t0 = (hi ? a2 : a0) + __shfl_xor(s0, 1);
    t1 = (hi ? a3 : a1) + __shfl_xor(s1, 1);
  }
  {
    const bool hi = kl & 2;
    const float s = hi ? t0 : t1;
    return (hi ? t1 : t0) + __shfl_xor(s, 2);
  }
}

// 256 threads = 4 waves = 1 wave/EU -> VGPR budget 512 (attribute-pinned).
// Hot weights (z, r, HA, HH = 192 half2) live in registers; cold weights
// (Wdgh, Wdgx, Why) live in LDS as f16 with per-thread pre-swizzled offsets.
// 3-barrier pipelined timestep; every thread participates in every segment:
//   SEG1: publish su = [x'|m|gh*h] (gamma dots carried in regs from SEG3 of
//         t-1), y(t-1), staging issue/write.
//   SEG2: z + r dots (one shared input window) + HA dot; butterfly reduce;
//         publish szg/srh/sha.
//   SEG3: HH dot + h update + outH; gamma dots for t+1 kept in registers.
__global__ __attribute__((amdgpu_flat_work_group_size(256, 256),
                          amdgpu_waves_per_eu(1, 1)))
void grud_persistent(
    const float* __restrict__ gIn,
    const float* __restrict__ xMean,
    const float* __restrict__ Wdgx, const float* __restrict__ bdgx,
    const float* __restrict__ Wdgh, const float* __restrict__ bdgh,
    const float* __restrict__ Wxz,  const float* __restrict__ Whz,
    const float* __restrict__ Wmz,  const float* __restrict__ bmz,
    const float* __restrict__ Wxr,  const float* __restrict__ Whr,
    const float* __restrict__ Wmr,
    const float* __restrict__ Wxh,  const float* __restrict__ Whh,
    const float* __restrict__ Wmh,  const float* __restrict__ bmh,
    const float* __restrict__ Why,  const float* __restrict__ bhy,
    float* __restrict__ out)
{
  const int tid = threadIdx.x;
  const int b   = blockIdx.x;

  __shared__ __align__(16) float sX[2][kTC][kIn];
  __shared__ __align__(16) float sM[2][kTC][kIn];
  __shared__ __align__(16) float sD[2][kTC][kIn];
  __shared__ __align__(16) float su[2 * kHid];   // swizzled: [x'(64)|m(64)|gh*h(128)]
  __shared__ __align__(16) float sh[kHid];       // swizzled
  __shared__ __align__(16) float srh[kHid];      // swizzled
  __shared__ __align__(16) float szg[kHid];      // swizzled
  __shared__ __align__(16) float sha[kHid];      // swizzled
  __shared__ __align__(16) __half2 lwDGH[4096];  // Wdgh f16, chunk-swizzled
  __shared__ __align__(16) __half2 lwDGX[2048];  // Wdgx f16
  __shared__ __align__(16) __half2 lwHY[4096];   // Why  f16

  // role coordinates
  const int kc  = tid & 15, cg = tid >> 4;   // z/r: 8 cols, K-chunk of 16
  const int kc8 = tid & 7,  g8 = tid >> 3;   // HA/HH: 4 cols, K-chunk of 16
  const int kq  = tid & 3,  oy = tid >> 2;   // y / dgx / x'-owner column
  const int kh  = tid & 1,  jg = tid >> 1;   // dgh column

  // ---------------- register weights (hot: z, r, HA, HH) ----------------
  __half2 wZ[8][8], wR[8][8];   // 8 cols x 16 k each
  __half2 wHA[4][8], wHH[4][8]; // 4 cols x 16 k each
  {
#pragma unroll
    for (int c = 0; c < 8; ++c) {
      const int j = cg * 8 + c;
#pragma unroll
      for (int p = 0; p < 8; ++p) {
        const int k = kc * 16 + 2 * p;
        const float z0 = (k < 64) ? Wxz[k * kHid + j]
                        : (k < 128) ? Wmz[(k - 64) * kHid + j]
                                    : Whz[(k - 128) * kHid + j];
        const float z1 = (k + 1 < 64) ? Wxz[(k + 1) * kHid + j]
                        : (k + 1 < 128) ? Wmz[(k + 1 - 64) * kHid + j]
                                        : Whz[(k + 1 - 128) * kHid + j];
        wZ[c][p] = __floats2half2_rn(z0, z1);
        const float r0 = (k < 64) ? Wxr[k * kHid + j]
                        : (k < 128) ? Wmr[(k - 64) * kHid + j]
                                    : Whr[(k - 128) * kHid + j];
        const float r1 = (k + 1 < 64) ? Wxr[(k + 1) * kHid + j]
                        : (k + 1 < 128) ? Wmr[(k + 1 - 64) * kHid + j]
                                        : Whr[(k + 1 - 128) * kHid + j];
        wR[c][p] = __floats2half2_rn(r0, r1);
      }
    }
  }
  {
#pragma unroll
    for (int c = 0; c < 4; ++c) {
      const int j = g8 * 4 + c;
#pragma unroll
      for (int p = 0; p < 8; ++p) {
        const int k = kc8 * 16 + 2 * p;
        const float h0 = (k < 64) ? Wxh[k * kHid + j] : Wmh[(k - 64) * kHid + j];
        const float h1 = (k + 1 < 64) ? Wxh[(k + 1) * kHid + j] : Wmh[(k + 1 - 64) * kHid + j];
        wHA[c][p] = __floats2half2_rn(h0, h1);
        wHH[c][p] = __floats2half2_rn(Whh[k * kHid + j], Whh[(k + 1) * kHid + j]);
      }
    }
  }

  // ---------------- LDS weights (cold: dgh, dgx, hy), each thread writes
  // exactly the chunks it will later read ----------------
#pragma unroll
  for (int p = 0; p < 16; ++p) {   // dgh: col jg, k = kh*32 + 2p
    const int k = kh * 32 + 2 * p;
    lwDGH[wswz(jg * 8 + kh * 4 + (p >> 2)) * 4 + (p & 3)] =
        __floats2half2_rn(Wdgh[k * kHid + jg], Wdgh[(k + 1) * kHid + jg]);
  }
#pragma unroll
  for (int p = 0; p < 8; ++p) {    // dgx: col oy, k = kq*16 + 2p
    const int k = kq * 16 + 2 * p;
    lwDGX[wswz(oy * 8 + kq * 2 + (p >> 2)) * 4 + (p & 3)] =
        __floats2half2_rn(Wdgx[k * kIn + oy], Wdgx[(k + 1) * kIn + oy]);
  }
#pragma unroll
  for (int p = 0; p < 16; ++p) {   // hy: col oy, k = kq*32 + 2p
    const int k = kq * 32 + 2 * p;
    lwHY[wswz(oy * 16 + kq * 4 + (p >> 2)) * 4 + (p & 3)] =
        __floats2half2_rn(Why[k * kOut + oy], Why[(k + 1) * kOut + oy]);
  }

  // ---------------- per-thread loop-invariant constants ----------------
  const int   jz     = cg * 8 + cl8(kc & 7);
  const float bZ     = bmz[jz];
  const int   idxZ   = swzi(jz);
  const int   idxZgh = swzi(128 + jz);
  const int   jh     = g8 * 4 + cl4(kc8 & 3);
  const float bH     = bmh[jh];
  const int   idxH   = swzi(jh);
  const int   idxHgh = swzi(128 + jh);
  const float bY     = bhy[oy];
  const float bGX    = bdgx[oy];
  const float xmv    = xMean[oy];
  const float bGH    = bdgh[jg];
  const int   ghRd   = swzi(jg),  ghWr = swzi(128 + jg);
  const int   xWr    = swzi(oy),  mWr  = swzi(64 + oy);

  int suOff[4], haOff[4], yOff[8], dghOff[4], hyOff[4], dgxOff[2];
#pragma unroll
  for (int q = 0; q < 4; ++q) {
    suOff[q]  = swzc(kc * 4 + q);                 // su window (K=256)
    haOff[q]  = swzc(kc8 * 4 + q);                // su[0:128] / srh window (K=128)
    dghOff[q] = wswz(jg * 8 + kh * 4 + q) * 4;    // h2 index
    hyOff[q]  = wswz(oy * 16 + kq * 4 + q) * 4;
  }
#pragma unroll
  for (int q = 0; q < 8; ++q) yOff[q] = swzc(kq * 8 + q);  // sh window (K=128)
#pragma unroll
  for (int q = 0; q < 2; ++q) dgxOff[q] = wswz(oy * 8 + kq * 2 + q) * 4;

  const float* gBase = gIn + (size_t)b * 3 * kIn * kT;
  float* outY = out + (size_t)b * kT * kOut;
  float* outH = out + (size_t)kBatch * kT * kOut + (size_t)b * kT * kHid;

  // gamma dots for the NEXT step: raw dot products (bias added at use)
  auto gammaDots = [&](int bs, int ts, float& gdh, float& gdx) {
    const float* dRow = &sD[bs][ts][0];
    float s = 0.0f;
#pragma unroll
    for (int wq = 0; wq < 4; ++wq) {
      const float4 w4 = *reinterpret_cast<const float4*>(&lwDGH[dghOff[wq]]);
      const __half2 w0 = __builtin_bit_cast(__half2, w4.x);
      const __half2 w1 = __builtin_bit_cast(__half2, w4.y);
      const __half2 w2 = __builtin_bit_cast(__half2, w4.z);
      const __half2 w3 = __builtin_bit_cast(__half2, w4.w);
      const float4 d0 = *reinterpret_cast<const float4*>(dRow + kh * 32 + wq * 8);
      const float4 d1 = *reinterpret_cast<const float4*>(dRow + kh * 32 + wq * 8 + 4);
      s = fmaf(__low2float(w0), d0.x, s); s = fmaf(__high2float(w0), d0.y, s);
      s = fmaf(__low2float(w1), d0.z, s); s = fmaf(__high2float(w1), d0.w, s);
      s = fmaf(__low2float(w2), d1.x, s); s = fmaf(__high2float(w2), d1.y, s);
      s = fmaf(__low2float(w3), d1.z, s); s = fmaf(__high2float(w3), d1.w, s);
    }
    s += __shfl_xor(s, 1);
    gdh = s;
    float s2 = 0.0f;
#pragma unroll
    for (int hq = 0; hq < 2; ++hq) {
      const float4 w4 = *reinterpret_cast<const float4*>(&lwDGX[dgxOff[hq]]);
      const __half2 w0 = __builtin_bit_cast(__half2, w4.x);
      const __half2 w1 = __builtin_bit_cast(__half2, w4.y);
      const __half2 w2 = __builtin_bit_cast(__half2, w4.z);
      const __half2 w3 = __builtin_bit_cast(__half2, w4.w);
      const float4 d0 = *reinterpret_cast<const float4*>(dRow + kq * 16 + hq * 8);
      const float4 d1 = *reinterpret_cast<const float4*>(dRow + kq * 16 + hq * 8 + 4);
      s2 = fmaf(__low2float(w0), d0.x, s2); s2 = fmaf(__high2float(w0), d0.y, s2);
      s2 = fmaf(__low2float(w1), d0.z, s2); s2 = fmaf(__high2float(w1), d0.w, s2);
      s2 = fmaf(__low2float(w2), d1.x, s2); s2 = fmaf(__high2float(w2), d1.y, s2);
      s2 = fmaf(__low2float(w3), d1.z, s2); s2 = fmaf(__high2float(w3), d1.w, s2);
    }
    s2 += __shfl_xor(s2, 1);
    s2 += __shfl_xor(s2, 2);
    gdx = s2;
  };

  auto doY = [&](int ty) {
    float s = 0.0f;
#pragma unroll
    for (int wq = 0; wq < 4; ++wq) {
      const float4 w4 = *reinterpret_cast<const float4*>(&lwHY[hyOff[wq]]);
      const __half2 w0 = __builtin_bit_cast(__half2, w4.x);
      const __half2 w1 = __builtin_bit_cast(__half2, w4.y);
      const __half2 w2 = __builtin_bit_cast(__half2, w4.z);
      const __half2 w3 = __builtin_bit_cast(__half2, w4.w);
      const float4 h0 = *reinterpret_cast<const float4*>(&sh[yOff[2 * wq]]);
      const float4 h1 = *reinterpret_cast<const float4*>(&sh[yOff[2 * wq + 1]]);
      s = fmaf(__low2float(w0), h0.x, s); s = fmaf(__high2float(w0), h0.y, s);
      s = fmaf(__low2float(w1), h0.z, s); s = fmaf(__high2float(w1), h0.w, s);
      s = fmaf(__low2float(w2), h1.x, s); s = fmaf(__high2float(w2), h1.y, s);
      s = fmaf(__low2float(w3), h1.z, s); s = fmaf(__high2float(w3), h1.w, s);
    }
    s += __shfl_xor(s, 1);
    s += __shfl_xor(s, 2);
    if (kq == 0) outY[(size_t)ty * kOut + oy] = sigm(s + bY);
  };

  // ---------------- prologue: stage chunk 0, init h ----------------
  if (tid < 192) {
    const int c = tid >> 6, i = tid & 63;
    const float4* src = reinterpret_cast<const float4*>(gBase + (size_t)(c * kIn + i) * kT);
    const float4 v0 = src[0], v1 = src[1];
    float* dst = (c == 0) ? &sX[0][0][0] : (c == 1) ? &sM[0][0][0] : &sD[0][0][0];
    dst[0 * kIn + i] = v0.x; dst[1 * kIn + i] = v0.y; dst[2 * kIn + i] = v0.z; dst[3 * kIn + i] = v0.w;
    dst[4 * kIn + i] = v1.x; dst[5 * kIn + i] = v1.y; dst[6 * kIn + i] = v1.z; dst[7 * kIn + i] = v1.w;
  }
  if (tid < kHid) sh[tid] = 0.0f;
  __syncthreads();

  float gdh, gdx;
  gammaDots(0, 0, gdh, gdx);
  float xl = 0.0f;
  float4 stv0 = {}, stv1 = {};

#pragma unroll 1
  for (int t = 0; t < kT; ++t) {
    const int tt  = t & 7;
    const int buf = (t >> 3) & 1;

    // ================= SEG1: publish su; y(t-1); staging =================
    if (kh == 0)
      su[ghWr] = __expf(-fmaxf(gdh + bGH, 0.0f)) * sh[ghRd];
    {
      const float x = sX[buf][tt][oy];
      const float m = sM[buf][tt][oy];
      xl = (m > 0.0f) ? x : xl;
      if (kq == 0) {
        const float gx = __expf(-fmaxf(gdx + bGX, 0.0f));
        su[xWr] = m * x + (1.0f - m) * (gx * xl + (1.0f - gx) * xmv);
        su[mWr] = m;
      }
    }
    if (t > 0) doY(t - 1);
    if (tid < 192) {
      if (tt == 0) {
        const int cs = (t >> 3) + 1;            // write staged chunk cs -> buffer cs&1
        if (cs < kChunks) {
          const int c = tid >> 6, i = tid & 63;
          if (t == 0) {                         // cold start: load directly
            const float4* src = reinterpret_cast<const float4*>(
                gBase + (size_t)(c * kIn + i) * kT + cs * kTC);
            stv0 = src[0]; stv1 = src[1];
          }
          float* dst = (c == 0) ? &sX[cs & 1][0][0] : (c == 1) ? &sM[cs & 1][0][0] : &sD[cs & 1][0][0];
          dst[0 * kIn + i] = stv0.x; dst[1 * kIn + i] = stv0.y;
          dst[2 * kIn + i] = stv0.z; dst[3 * kIn + i] = stv0.w;
          dst[4 * kIn + i] = stv1.x; dst[5 * kIn + i] = stv1.y;
          dst[6 * kIn + i] = stv1.z; dst[7 * kIn + i] = stv1.w;
        }
      } else if (tt == 7) {
        const int cs = (t >> 3) + 2;            // issue loads ~3 barriers early
        if (cs < kChunks) {
          const int c = tid >> 6, i = tid & 63;
          const float4* src = reinterpret_cast<const float4*>(
              gBase + (size_t)(c * kIn + i) * kT + cs * kTC);
          stv0 = src[0]; stv1 = src[1];
        }
      }
    }
    __syncthreads();

    // ================= SEG2: z + r dots (shared window) + HA =================
    {
      float u[16];
      {
        const float4 c0 = *reinterpret_cast<const float4*>(&su[suOff[0]]);
        const float4 c1 = *reinterpret_cast<const float4*>(&su[suOff[1]]);
        const float4 c2 = *reinterpret_cast<const float4*>(&su[suOff[2]]);
        const float4 c3 = *reinterpret_cast<const float4*>(&su[suOff[3]]);
        u[0]=c0.x;  u[1]=c0.y;  u[2]=c0.z;  u[3]=c0.w;
        u[4]=c1.x;  u[5]=c1.y;  u[6]=c1.z;  u[7]=c1.w;
        u[8]=c2.x;  u[9]=c2.y;  u[10]=c2.z; u[11]=c2.w;
        u[12]=c3.x; u[13]=c3.y; u[14]=c3.z; u[15]=c3.w;
      }
      float az[8], ar[8];
#pragma unroll
      for (int c = 0; c < 8; ++c) {
        float sz = 0.0f, sr = 0.0f;
#pragma unroll
        for (int p = 0; p < 8; ++p) {
          const float lo = u[2 * p], hi = u[2 * p + 1];
          sz = fmaf(__low2float(wZ[c][p]),  lo, sz);
          sz = fmaf(__high2float(wZ[c][p]), hi, sz);
          sr = fmaf(__low2float(wR[c][p]),  lo, sr);
          sr = fmaf(__high2float(wR[c][p]), hi, sr);
        }
        az[c] = sz; ar[c] = sr;
      }
      float z = rs8(az[0], az[1], az[2], az[3], az[4], az[5], az[6], az[7], kc & 7);
      z += __shfl_xor(z, 8);
      float r = rs8(ar[0], ar[1], ar[2], ar[3], ar[4], ar[5], ar[6], ar[7], kc & 7);
      r += __shfl_xor(r, 8);

      // HA: [x'|m] part of h_tilde preactivation
      float v[16];
      {
        const float4 c0 = *reinterpret_cast<const float4*>(&su[haOff[0]]);
        const float4 c1 = *reinterpret_cast<const float4*>(&su[haOff[1]]);
        const float4 c2 = *reinterpret_cast<const float4*>(&su[haOff[2]]);
        const float4 c3 = *reinterpret_cast<const float4*>(&su[haOff[3]]);
        v[0]=c0.x;  v[1]=c0.y;  v[2]=c0.z;  v[3]=c0.w;
        v[4]=c1.x;  v[5]=c1.y;  v[6]=c1.z;  v[7]=c1.w;
        v[8]=c2.x;  v[9]=c2.y;  v[10]=c2.z; v[11]=c2.w;
        v[12]=c3.x; v[13]=c3.y; v[14]=c3.z; v[15]=c3.w;
      }
      float ah[4];
#pragma unroll
      for (int c = 0; c < 4; ++c) {
        float s = 0.0f;
#pragma unroll
        for (int p = 0; p < 8; ++p) {
          s = fmaf(__low2float(wHA[c][p]),  v[2 * p],     s);
          s = fmaf(__high2float(wHA[c][p]), v[2 * p + 1], s);
        }
        ah[c] = s;
      }
      float hv = rs4(ah[0], ah[1], ah[2], ah[3], kc8 & 3);
      hv += __shfl_xor(hv, 4);
      if (kc8 < 4) sha[idxH] = hv + bH;
      if (kc < 8) {
        szg[idxZ] = sigm(z + bZ);
        srh[idxZ] = sigm(r) * su[idxZgh];
      }
    }
    __syncthreads();

    // ================= SEG3: HH dot + h update; gamma(t+1) =================
    {
      float v[16];
      {
        const float4 c0 = *reinterpret_cast<const float4*>(&srh[haOff[0]]);
        const float4 c1 = *reinterpret_cast<const float4*>(&srh[haOff[1]]);
        const float4 c2 = *reinterpret_cast<const float4*>(&srh[haOff[2]]);
        const float4 c3 = *reinterpret_cast<const float4*>(&srh[haOff[3]]);
        v[0]=c0.x;  v[1]=c0.y;  v[2]=c0.z;  v[3]=c0.w;
        v[4]=c1.x;  v[5]=c1.y;  v[6]=c1.z;  v[7]=c1.w;
        v[8]=c2.x;  v[9]=c2.y;  v[10]=c2.z; v[11]=c2.w;
        v[12]=c3.x; v[13]=c3.y; v[14]=c3.z; v[15]=c3.w;
      }
      float ah[4];
#pragma unroll
      for (int c = 0; c < 4; ++c) {
        float s = 0.0f;
#pragma unroll
        for (int p = 0; p < 8; ++p) {
          s = fmaf(__low2float(wHH[c][p]),  v[2 * p],     s);
          s = fmaf(__high2float(wHH[c][p]), v[2 * p + 1], s);
        }
        ah[c] = s;
      }
      float hh = rs4(ah[0], ah[1], ah[2], ah[3], kc8 & 3);
      hh += __shfl_xor(hh, 4);
      if (kc8 < 4) {
        const float zz  = szg[idxH];
        const float hav = sha[idxH];
        const float hp  = su[idxHgh];
        const float hn  = (1.0f - zz) * hp + zz * tanhf_(hav + hh);
        sh[idxH] = hn;
        outH[(size_t)t * kHid + jh] = hn;
      }
    }
    if (t + 1 < kT) {
      const int tn = t + 1;
      gammaDots((tn >> 3) & 1, tn & 7, gdh, gdx);
    }
    __syncthreads();
  }

  // epilogue: y for the final step
  doY(kT - 1);
}

} // namespace

extern "C" void kernel_launch(void* const* d_in, const int* in_sizes, int n_in,
                              void* d_out, int out_size, void* d_ws, size_t ws_size,
                              hipStream_t stream) {
  const float* gIn   = (const float*)d_in[0];
  const float* xMean = (const float*)d_in[1];
  const float* Wdgx  = (const float*)d_in[2];
  const float* bdgx  = (const float*)d_in[3];
  const float* Wdgh  = (const float*)d_in[4];
  const float* bdgh  = (const float*)d_in[5];
  const float* Wxz   = (const float*)d_in[6];
  const float* Whz   = (const float*)d_in[7];
  const float* Wmz   = (const float*)d_in[8];
  const float* bmz   = (const float*)d_in[9];
  const float* Wxr   = (const float*)d_in[10];
  const float* Whr   = (const float*)d_in[11];
  const float* Wmr   = (const float*)d_in[12];
  const float* Wxh   = (const float*)d_in[13];
  const float* Whh   = (const float*)d_in[14];
  const float* Wmh   = (const float*)d_in[15];
  const float* bmh   = (const float*)d_in[16];
  const float* Why   = (const float*)d_in[17];
  const float* bhy   = (const float*)d_in[18];

  grud_persistent<<<dim3(256), dim3(256), 0, stream>>>(
      gIn, xMean, Wdgx, bdgx, Wdgh, bdgh, Wxz, Whz, Wmz, bmz,
      Wxr, Whr, Wmr, Wxh, Whh, Wmh, bmh, Why, bhy, (float*)d_out);
}